// Round 1
// baseline (135.570 us; speedup 1.0000x reference)
//
#include <hip/hip_runtime.h>
#include <hip/hip_bf16.h>

// output[b, j, h, w] = 0.25f * x[b, perm[j], h, w]
// x: [32, 64, 128, 128] f32, perm: [256] i32, out: [32, 256, 128, 128] f32
//
// Plane size = 128*128 = 16384 floats = 4096 float4. Channels per batch:
// in=64, out=256. All accesses coalesced float4.

__global__ void ChannelRandomPaddingSkip_24867860644348_kernel(
    const float4* __restrict__ x, const int* __restrict__ perm,
    float4* __restrict__ out, int total_vec4) {
  const float s = 0.25f;  // SCALE * WEIGHT = 1.0 * (1/4)
  int idx = blockIdx.x * blockDim.x + threadIdx.x;
  int stride = gridDim.x * blockDim.x;
  for (int o = idx; o < total_vec4; o += stride) {
    int plane  = o >> 12;        // 4096 float4 per plane
    int within = o & 4095;
    int b = plane >> 8;          // 256 output channels per batch
    int j = plane & 255;
    int c = perm[j];             // source input channel (0..63)
    float4 v = x[(((b << 6) + c) << 12) + within];
    float4 r;
    r.x = v.x * s; r.y = v.y * s; r.z = v.z * s; r.w = v.w * s;
    out[o] = r;
  }
}

extern "C" void kernel_launch(void* const* d_in, const int* in_sizes, int n_in,
                              void* d_out, int out_size, void* d_ws, size_t ws_size,
                              hipStream_t stream) {
  const float4* x   = (const float4*)d_in[0];
  const int* perm   = (const int*)d_in[1];
  float4* out       = (float4*)d_out;

  int total_vec4 = out_size / 4;           // 134217728 / 4 = 33554432
  int block = 256;
  int grid = (total_vec4 + block - 1) / block;
  if (grid > 2048) grid = 2048;            // grid-stride the rest
  ChannelRandomPaddingSkip_24867860644348_kernel<<<grid, block, 0, stream>>>(
      x, perm, out, total_vec4);
}

// Round 3
// 104.637 us; speedup vs baseline: 1.2956x; 1.2956x over previous
//
#include <hip/hip_runtime.h>
#include <hip/hip_bf16.h>

// output[b, j, h, w] = 0.25f * x[b, perm[j], h, w]
// x: [32, 64, 128, 128] f32, perm: [256] i32, out: [32, 256, 128, 128] f32
//
// Scatter formulation: read each input vec4 ONCE, write its 4 replica
// destinations from registers (perm = 4 concatenated permutations of 0..63,
// so every input channel appears exactly once per 64-wide replica block).
// Inverse map built per-block in LDS. Non-temporal stores: output is never
// re-read, keep it out of L2/L3 so the x stream stays cached.

typedef float vfloat4 __attribute__((ext_vector_type(4)));  // clang-native vec for nontemporal builtin

__global__ __launch_bounds__(256) void ChannelRandomPaddingSkip_24867860644348_kernel(
    const vfloat4* __restrict__ x, const int* __restrict__ perm,
    vfloat4* __restrict__ out, int total_in_vec4) {
  __shared__ int inv[256];  // inv[k*64 + c] = output channel j in replica k with perm[j]==c
  {
    int t = threadIdx.x;            // block=256
    int c = perm[t];                // 0..63
    inv[(t & ~63) | c] = t;         // (t>>6)*64 + c
  }
  __syncthreads();

  const float s = 0.25f;  // SCALE * WEIGHT
  int idx = blockIdx.x * blockDim.x + threadIdx.x;
  int stride = gridDim.x * blockDim.x;
  for (int o = idx; o < total_in_vec4; o += stride) {
    int plane  = o >> 12;        // 4096 float4 per 128x128 plane
    int within = o & 4095;
    int b = plane >> 6;          // 64 input channels per batch
    int c = plane & 63;
    vfloat4 v = x[o];
    vfloat4 r = v * s;
    int obase = (b << 20) | within;          // b*256*4096 + within
#pragma unroll
    for (int k = 0; k < 4; ++k) {
      int j = inv[(k << 6) | c];             // output channel for replica k
      __builtin_nontemporal_store(r, &out[obase + (j << 12)]);
    }
  }
}

extern "C" void kernel_launch(void* const* d_in, const int* in_sizes, int n_in,
                              void* d_out, int out_size, void* d_ws, size_t ws_size,
                              hipStream_t stream) {
  const vfloat4* x   = (const vfloat4*)d_in[0];
  const int* perm    = (const int*)d_in[1];
  vfloat4* out       = (vfloat4*)d_out;

  int total_in_vec4 = in_sizes[0] / 4;     // 33554432 / 4 = 8388608
  int block = 256;
  int grid = (total_in_vec4 + block - 1) / block;
  if (grid > 2048) grid = 2048;            // grid-stride the rest
  ChannelRandomPaddingSkip_24867860644348_kernel<<<grid, block, 0, stream>>>(
      x, perm, out, total_in_vec4);
}